// Round 4
// baseline (172.192 us; speedup 1.0000x reference)
//
#include <hip/hip_runtime.h>
#include <hip/hip_bf16.h>
#include <stdint.h>

#define NROWS 4096
#define DIM   1024
#define NCLS  64
#define NTB   32            // 4096/128 tile-blocks per axis
#define NTRI  528           // 32*33/2 upper-triangle tiles
#define NCHUNK 64           // 64-col partial chunks per row
#define CONV_BLOCKS 2048    // convert part of fused prep kernel
#define PREP_BLOCKS 1024

constexpr float TEMP_INV = 1.0f / 0.07f;

typedef __attribute__((ext_vector_type(8))) short  bf16x8;
typedef __attribute__((ext_vector_type(4))) float  f32x4;

__device__ inline void gload_lds16(const void* g, void* l) {
    __builtin_amdgcn_global_load_lds(
        (const __attribute__((address_space(1))) void*)g,
        (__attribute__((address_space(3))) void*)l, 16, 0, 0);
}

// ---------------- kernel 1: fused convert (bf16 pre-swizzle) + prep ----------
__global__ void prep_convert_kernel(const float* __restrict__ emb,
                                    const float* __restrict__ logits,
                                    const int* __restrict__ labels,
                                    __hip_bfloat16* __restrict__ embb,
                                    uint64_t* __restrict__ maskout,
                                    float* __restrict__ wout,
                                    float* __restrict__ bceout,
                                    float* __restrict__ accum) {
    const int b = blockIdx.x;
    if (b < CONV_BLOCKS) {
        // fp32 -> bf16 copy, PRE-SWIZZLED (slot ^= row&7 within each 64-elem K-block)
        const int t   = b * 256 + threadIdx.x;
        const int row = t >> 7;
        const int sl  = t & 127;
        const int kb  = sl >> 3;
        const int s   = sl & 7;
        const float* src = emb + (size_t)row * DIM + kb * 64 + s * 8;
        const float4 a = *(const float4*)src;
        const float4 bb = *(const float4*)(src + 4);
        const int sd = s ^ (row & 7);
        union { __hip_bfloat16 h[8]; float4 v; } u;
        u.h[0] = __float2bfloat16(a.x);  u.h[1] = __float2bfloat16(a.y);
        u.h[2] = __float2bfloat16(a.z);  u.h[3] = __float2bfloat16(a.w);
        u.h[4] = __float2bfloat16(bb.x); u.h[5] = __float2bfloat16(bb.y);
        u.h[6] = __float2bfloat16(bb.z); u.h[7] = __float2bfloat16(bb.w);
        *(float4*)(embb + (size_t)row * DIM + kb * 64 + sd * 8) = u.v;
    } else {
        const int pb   = b - CONV_BLOCKS;
        const int row  = pb * 4 + (threadIdx.x >> 6);
        const int lane = threadIdx.x & 63;
        if (pb == 0 && threadIdx.x < 8) accum[threadIdx.x] = 0.0f;  // zero accum+counter
        const float l = logits[row * NCLS + lane];
        const int   y = labels[row * NCLS + lane];
        const float yf = (float)y;

        float bce = fmaxf(l, 0.0f) - l * yf + log1pf(expf(-fabsf(l)));
        const float pr = 1.0f / (1.0f + expf(-l));
        const float ent = -(pr * logf(pr + 1e-8f) + (1.0f - pr) * logf(1.0f - pr + 1e-8f));
        float entw = ent * yf;
        float ycnt = yf;

        #pragma unroll
        for (int off = 32; off; off >>= 1) {
            bce  += __shfl_down(bce, off);
            entw += __shfl_down(entw, off);
            ycnt += __shfl_down(ycnt, off);
        }
        const uint64_t m = __ballot(y != 0);
        if (lane == 0) {
            maskout[row] = m;
            wout[row]    = entw / (ycnt + 1e-8f);
            bceout[row]  = bce;
        }
    }
}

// ---------------- kernel 2: MFMA sim tiles, counted-vmcnt 2-deep pipeline ----
__device__ inline bf16x8 frag_read(const unsigned char* tile, int row, int ks, int lane) {
    const int slot = (ks * 4 + (lane >> 4)) ^ (row & 7);
    return *(const bf16x8*)(tile + row * 128 + slot * 16);
}

__device__ inline void stage_tile(const __hip_bfloat16* __restrict__ embb,
                                  size_t arow0, size_t brow0, int kb,
                                  unsigned char* As, unsigned char* Bs, int tid) {
    const int lr  = tid >> 3;          // staging row 0..31
    const int lce = (tid & 7) * 8;     // staging col (elements)
    #pragma unroll
    for (int is = 0; is < 4; ++is) {
        const int r = is * 32 + lr;
        gload_lds16(embb + (arow0 + r) * DIM + kb * 64 + lce, As + is * 4096 + tid * 16);
        gload_lds16(embb + (brow0 + r) * DIM + kb * 64 + lce, Bs + is * 4096 + tid * 16);
    }
}

__device__ inline void compute_tile(const unsigned char* As, const unsigned char* Bs,
                                    int wm, int wn, int lane, f32x4 acc[4][4]) {
    __builtin_amdgcn_s_setprio(1);
    #pragma unroll
    for (int ks = 0; ks < 2; ++ks) {
        bf16x8 af[4], bfr[4];
        #pragma unroll
        for (int f = 0; f < 4; ++f) {
            af[f]  = frag_read(As, wm * 64 + f * 16 + (lane & 15), ks, lane);
            bfr[f] = frag_read(Bs, wn * 64 + f * 16 + (lane & 15), ks, lane);
        }
        #pragma unroll
        for (int i = 0; i < 4; ++i)
            #pragma unroll
            for (int j = 0; j < 4; ++j)
                acc[i][j] = __builtin_amdgcn_mfma_f32_16x16x32_bf16(af[i], bfr[j], acc[i][j], 0, 0, 0);
    }
    __builtin_amdgcn_s_setprio(0);
}

__global__ __launch_bounds__(256)
void sim_kernel(const __hip_bfloat16* __restrict__ embb,
                const uint64_t* __restrict__ mask,
                float4* __restrict__ partial) {
    __shared__ __align__(16) unsigned char A0[16384];   // [128 rows][64 bf16] swizzled
    __shared__ __align__(16) unsigned char B0[16384];
    __shared__ __align__(16) unsigned char A1[16384];
    __shared__ __align__(16) unsigned char B1[16384];
    __shared__ uint64_t rmaskS[128];
    __shared__ uint64_t cmaskS[128];

    // linear block id -> upper-triangle (by, bx), by <= bx
    int t = blockIdx.x, by = 0;
    while (t >= NTB - by) { t -= NTB - by; ++by; }
    const int bx = by + t;

    const int tid  = threadIdx.x;
    const int lane = tid & 63;
    const int wid  = tid >> 6;
    const int wm   = wid >> 1;          // wave row-half
    const int wn   = wid & 1;           // wave col-half

    if (tid < 128)      rmaskS[tid]       = mask[by * 128 + tid];
    else                cmaskS[tid - 128] = mask[bx * 128 + (tid - 128)];

    f32x4 acc[4][4];
    #pragma unroll
    for (int i = 0; i < 4; ++i)
        #pragma unroll
        for (int j = 0; j < 4; ++j) acc[i][j] = (f32x4)0.0f;

    const size_t arow0 = (size_t)by * 128;
    const size_t brow0 = (size_t)bx * 128;

    // ---- prologue: 2 tiles in flight (16 loads/thread outstanding) ----
    stage_tile(embb, arow0, brow0, 0, A0, B0, tid);
    stage_tile(embb, arow0, brow0, 1, A1, B1, tid);

    // ---- counted-vmcnt pipeline: never drain to 0 in steady state ----
    // entering phase t: outstanding = tiles t, t+1 (16 loads). vmcnt(8) -> t landed.
    #pragma unroll 1
    for (int kb2 = 0; kb2 < 7; ++kb2) {
        // phase A: compute tile 2*kb2 (buf0), stage 2*kb2+2 into buf0
        asm volatile("s_waitcnt vmcnt(8)" ::: "memory");
        __builtin_amdgcn_s_barrier();
        compute_tile(A0, B0, wm, wn, lane, acc);
        __builtin_amdgcn_s_barrier();
        stage_tile(embb, arow0, brow0, 2 * kb2 + 2, A0, B0, tid);
        // phase B: compute tile 2*kb2+1 (buf1), stage 2*kb2+3 into buf1
        asm volatile("s_waitcnt vmcnt(8)" ::: "memory");
        __builtin_amdgcn_s_barrier();
        compute_tile(A1, B1, wm, wn, lane, acc);
        __builtin_amdgcn_s_barrier();
        stage_tile(embb, arow0, brow0, 2 * kb2 + 3, A1, B1, tid);
    }
    // tile 14: outstanding = {14,15}; vmcnt(8) releases 14
    asm volatile("s_waitcnt vmcnt(8)" ::: "memory");
    __builtin_amdgcn_s_barrier();
    compute_tile(A0, B0, wm, wn, lane, acc);
    // tile 15: only its 8 remain -> full drain
    asm volatile("s_waitcnt vmcnt(0)" ::: "memory");
    __builtin_amdgcn_s_barrier();
    compute_tile(A1, B1, wm, wn, lane, acc);

    // C/D layout: col = lane&15, row = (lane>>4)*4 + reg   [m89-verified]
    const int lg = lane >> 4;
    const int lc = lane & 15;

    uint64_t cmR[4];
    #pragma unroll
    for (int nf = 0; nf < 4; ++nf) cmR[nf] = cmaskS[wn * 64 + nf * 16 + lc];

    // ---- row epilogue: per-row (m,p,s) over this tile's cols (per wave: 64) ----
    #pragma unroll
    for (int mf = 0; mf < 4; ++mf) {
        #pragma unroll
        for (int rg = 0; rg < 4; ++rg) {
            const int r    = wm * 64 + mf * 16 + lg * 4 + rg;
            const int grow = by * 128 + r;
            const uint64_t rm = rmaskS[r];
            float v[4]; bool od[4], pp[4];
            float mx = -1e30f;
            #pragma unroll
            for (int nf = 0; nf < 4; ++nf) {
                const int gcol = bx * 128 + wn * 64 + nf * 16 + lc;
                v[nf]  = acc[mf][nf][rg] * TEMP_INV;
                od[nf] = (gcol != grow);
                pp[nf] = od[nf] && ((rm & cmR[nf]) != 0ull);
                if (od[nf]) mx = fmaxf(mx, v[nf]);
            }
            #pragma unroll
            for (int o = 1; o < 16; o <<= 1) mx = fmaxf(mx, __shfl_xor(mx, o));
            float sp = 0.0f, ss = 0.0f;
            #pragma unroll
            for (int nf = 0; nf < 4; ++nf) {
                if (od[nf]) {
                    const float e = __expf(v[nf] - mx);
                    ss += e;
                    if (pp[nf]) sp += e;
                }
            }
            #pragma unroll
            for (int o = 1; o < 16; o <<= 1) { sp += __shfl_xor(sp, o); ss += __shfl_xor(ss, o); }
            if (lc == 0)
                partial[(size_t)grow * NCHUNK + bx * 2 + wn] = make_float4(mx, sp, ss, 0.0f);
        }
    }

    // ---- col epilogue (symmetric write), skip on diagonal tiles ----
    if (bx != by) {
        #pragma unroll
        for (int nf = 0; nf < 4; ++nf) {
            const int gcol = bx * 128 + wn * 64 + nf * 16 + lc;
            const uint64_t cm = cmR[nf];
            float v[16]; bool pp[16];
            float mx = -1e30f;
            #pragma unroll
            for (int mf = 0; mf < 4; ++mf)
                #pragma unroll
                for (int rg = 0; rg < 4; ++rg) {
                    const int idx = mf * 4 + rg;
                    v[idx] = acc[mf][nf][rg] * TEMP_INV;     // rows != cols here, all od
                    pp[idx] = ((rmaskS[wm * 64 + mf * 16 + lg * 4 + rg] & cm) != 0ull);
                    mx = fmaxf(mx, v[idx]);
                }
            mx = fmaxf(mx, __shfl_xor(mx, 16));
            mx = fmaxf(mx, __shfl_xor(mx, 32));
            float sp = 0.0f, ss = 0.0f;
            #pragma unroll
            for (int idx = 0; idx < 16; ++idx) {
                const float e = __expf(v[idx] - mx);
                ss += e;
                if (pp[idx]) sp += e;
            }
            sp += __shfl_xor(sp, 16); sp += __shfl_xor(sp, 32);
            ss += __shfl_xor(ss, 16); ss += __shfl_xor(ss, 32);
            if (lane < 16)
                partial[(size_t)gcol * NCHUNK + by * 2 + wm] = make_float4(mx, sp, ss, 0.0f);
        }
    }
}

// ---------------- kernel 3: merge + final (last-block-done) ------------------
__global__ void merge_kernel(const float4* __restrict__ partial,
                             const float* __restrict__ w,
                             const float* __restrict__ bce,
                             float* __restrict__ accum,   // [0]=loss [1]=valid [2]=bce
                             int* __restrict__ cnt,       // accum[7] slot
                             float* __restrict__ out) {
    const int tid  = threadIdx.x;
    const int lane = tid & 63;
    const int wv   = tid >> 6;
    const int row  = blockIdx.x * 4 + wv;

    const float4 q = partial[(size_t)row * NCHUNK + lane];   // lane == chunk
    float m = q.x, p = q.y, s = q.z;
    #pragma unroll
    for (int o = 1; o < 64; o <<= 1) {
        const float om = __shfl_xor(m, o);
        const float op = __shfl_xor(p, o);
        const float os = __shfl_xor(s, o);
        const float M  = fmaxf(m, om);
        const float e1 = __expf(m - M);
        const float e2 = __expf(om - M);
        p = p * e1 + op * e2;
        s = s * e1 + os * e2;
        m = M;
    }
    __shared__ float rl[4], rv[4], rb[4];
    if (lane == 0) {
        float li = 0.0f, va = 0.0f;
        if (p > 0.0f) { va = 1.0f; li = -logf(p / (s + 1e-8f)) * w[row]; }
        rl[wv] = li; rv[wv] = va; rb[wv] = bce[row];
    }
    __syncthreads();
    if (tid == 0) {
        atomicAdd(&accum[0], rl[0] + rl[1] + rl[2] + rl[3]);
        atomicAdd(&accum[1], rv[0] + rv[1] + rv[2] + rv[3]);
        atomicAdd(&accum[2], rb[0] + rb[1] + rb[2] + rb[3]);
        __threadfence();
        const int prev = atomicAdd(cnt, 1);
        if (prev == (NROWS / 4) - 1) {              // last block: finalize
            const float L = atomicAdd(&accum[0], 0.0f);
            const float V = atomicAdd(&accum[1], 0.0f);
            const float B = atomicAdd(&accum[2], 0.0f);
            out[0] = B / (float)(NROWS * NCLS) + (V > 0.0f ? L / V : 0.0f);
        }
    }
}

extern "C" void kernel_launch(void* const* d_in, const int* in_sizes, int n_in,
                              void* d_out, int out_size, void* d_ws, size_t ws_size,
                              hipStream_t stream) {
    const float* emb    = (const float*)d_in[0];
    const float* logits = (const float*)d_in[1];
    const int*   labels = (const int*)d_in[2];
    float* out = (float*)d_out;

    uint8_t* ws = (uint8_t*)d_ws;
    uint64_t*       mask  = (uint64_t*)(ws);                    // 32 KB
    float*          wrow  = (float*)(ws + 0x8000);              // 16 KB
    float*          bcer  = (float*)(ws + 0xC000);              // 16 KB
    float*          accum = (float*)(ws + 0x10000);             // 8 floats (acc + cnt)
    float4*         part  = (float4*)(ws + 0x20000);            // 4 MB
    __hip_bfloat16* embb  = (__hip_bfloat16*)(ws + 0x420000);   // 8 MB
    int*            cnt   = (int*)(accum + 7);

    prep_convert_kernel<<<CONV_BLOCKS + PREP_BLOCKS, 256, 0, stream>>>(
        emb, logits, labels, embb, mask, wrow, bcer, accum);
    sim_kernel<<<NTRI, 256, 0, stream>>>(embb, mask, part);
    merge_kernel<<<NROWS / 4, 256, 0, stream>>>(part, wrow, bcer, accum, cnt, out);
}

// Round 5
// 119.862 us; speedup vs baseline: 1.4366x; 1.4366x over previous
//
#include <hip/hip_runtime.h>
#include <hip/hip_bf16.h>
#include <stdint.h>

#define NROWS 4096
#define DIM   1024
#define NCLS  64
#define NTB   32            // 4096/128 tile-blocks per axis
#define NTRI  528           // 32*33/2 upper-triangle tiles
#define CONV_BLOCKS 2048    // convert part of fused prep kernel
#define PREP_BLOCKS 1024

constexpr float TEMP_INV = 1.0f / 0.07f;

typedef __attribute__((ext_vector_type(8))) short  bf16x8;
typedef __attribute__((ext_vector_type(4))) float  f32x4;

__device__ inline void gload_lds16(const void* g, void* l) {
    __builtin_amdgcn_global_load_lds(
        (const __attribute__((address_space(1))) void*)g,
        (__attribute__((address_space(3))) void*)l, 16, 0, 0);
}

// ---------------- kernel 1: fused convert (bf16 pre-swizzle) + prep ----------
__global__ void prep_convert_kernel(const float* __restrict__ emb,
                                    const float* __restrict__ logits,
                                    const int* __restrict__ labels,
                                    __hip_bfloat16* __restrict__ embb,
                                    uint64_t* __restrict__ maskout,
                                    float* __restrict__ wout,
                                    float* __restrict__ bceout,
                                    float* __restrict__ psum,
                                    float* __restrict__ nsum) {
    const int b = blockIdx.x;
    if (b < CONV_BLOCKS) {
        // fp32 -> bf16 copy, PRE-SWIZZLED (slot ^= row&7 within each 64-elem K-block)
        const int t   = b * 256 + threadIdx.x;
        const int row = t >> 7;
        const int sl  = t & 127;
        const int kb  = sl >> 3;
        const int s   = sl & 7;
        const float* src = emb + (size_t)row * DIM + kb * 64 + s * 8;
        const float4 a = *(const float4*)src;
        const float4 bb = *(const float4*)(src + 4);
        const int sd = s ^ (row & 7);
        union { __hip_bfloat16 h[8]; float4 v; } u;
        u.h[0] = __float2bfloat16(a.x);  u.h[1] = __float2bfloat16(a.y);
        u.h[2] = __float2bfloat16(a.z);  u.h[3] = __float2bfloat16(a.w);
        u.h[4] = __float2bfloat16(bb.x); u.h[5] = __float2bfloat16(bb.y);
        u.h[6] = __float2bfloat16(bb.z); u.h[7] = __float2bfloat16(bb.w);
        *(float4*)(embb + (size_t)row * DIM + kb * 64 + sd * 8) = u.v;
    } else {
        const int pb   = b - CONV_BLOCKS;
        const int row  = pb * 4 + (threadIdx.x >> 6);
        const int lane = threadIdx.x & 63;
        // zero the per-row accumulators (d_ws is poisoned before every launch)
        if (threadIdx.x < 4)       psum[pb * 4 + threadIdx.x] = 0.0f;
        else if (threadIdx.x < 8)  nsum[pb * 4 + threadIdx.x - 4] = 0.0f;

        const float l = logits[row * NCLS + lane];
        const int   y = labels[row * NCLS + lane];
        const float yf = (float)y;

        float bce = fmaxf(l, 0.0f) - l * yf + log1pf(expf(-fabsf(l)));
        const float pr = 1.0f / (1.0f + expf(-l));
        const float ent = -(pr * logf(pr + 1e-8f) + (1.0f - pr) * logf(1.0f - pr + 1e-8f));
        float entw = ent * yf;
        float ycnt = yf;

        #pragma unroll
        for (int off = 32; off; off >>= 1) {
            bce  += __shfl_down(bce, off);
            entw += __shfl_down(entw, off);
            ycnt += __shfl_down(ycnt, off);
        }
        const uint64_t m = __ballot(y != 0);
        if (lane == 0) {
            maskout[row] = m;
            wout[row]    = entw / (ycnt + 1e-8f);
            bceout[row]  = bce;
        }
    }
}

// ---------------- kernel 2: MFMA sim tiles, counted-vmcnt 2-deep pipeline ----
__device__ inline bf16x8 frag_read(const unsigned char* tile, int row, int ks, int lane) {
    const int slot = (ks * 4 + (lane >> 4)) ^ (row & 7);
    return *(const bf16x8*)(tile + row * 128 + slot * 16);
}

__device__ inline void stage_tile(const __hip_bfloat16* __restrict__ embb,
                                  size_t arow0, size_t brow0, int kb,
                                  unsigned char* As, unsigned char* Bs, int tid) {
    const int lr  = tid >> 3;          // staging row 0..31
    const int lce = (tid & 7) * 8;     // staging col (elements)
    #pragma unroll
    for (int is = 0; is < 4; ++is) {
        const int r = is * 32 + lr;
        gload_lds16(embb + (arow0 + r) * DIM + kb * 64 + lce, As + is * 4096 + tid * 16);
        gload_lds16(embb + (brow0 + r) * DIM + kb * 64 + lce, Bs + is * 4096 + tid * 16);
    }
}

__device__ inline void compute_tile(const unsigned char* As, const unsigned char* Bs,
                                    int wm, int wn, int lane, f32x4 acc[4][4]) {
    __builtin_amdgcn_s_setprio(1);
    #pragma unroll
    for (int ks = 0; ks < 2; ++ks) {
        bf16x8 af[4], bfr[4];
        #pragma unroll
        for (int f = 0; f < 4; ++f) {
            af[f]  = frag_read(As, wm * 64 + f * 16 + (lane & 15), ks, lane);
            bfr[f] = frag_read(Bs, wn * 64 + f * 16 + (lane & 15), ks, lane);
        }
        #pragma unroll
        for (int i = 0; i < 4; ++i)
            #pragma unroll
            for (int j = 0; j < 4; ++j)
                acc[i][j] = __builtin_amdgcn_mfma_f32_16x16x32_bf16(af[i], bfr[j], acc[i][j], 0, 0, 0);
    }
    __builtin_amdgcn_s_setprio(0);
}

__global__ __launch_bounds__(256)
void sim_kernel(const __hip_bfloat16* __restrict__ embb,
                const uint64_t* __restrict__ mask,
                float* __restrict__ psum,
                float* __restrict__ nsum) {
    __shared__ __align__(16) unsigned char A0[16384];   // [128 rows][64 bf16] swizzled
    __shared__ __align__(16) unsigned char B0[16384];
    __shared__ __align__(16) unsigned char A1[16384];
    __shared__ __align__(16) unsigned char B1[16384];
    __shared__ uint64_t rmaskS[128];
    __shared__ uint64_t cmaskS[128];

    // linear block id -> upper-triangle (by, bx), by <= bx
    int t = blockIdx.x, by = 0;
    while (t >= NTB - by) { t -= NTB - by; ++by; }
    const int bx = by + t;

    const int tid  = threadIdx.x;
    const int lane = tid & 63;
    const int wid  = tid >> 6;
    const int wm   = wid >> 1;          // wave row-half
    const int wn   = wid & 1;           // wave col-half

    if (tid < 128)      rmaskS[tid]       = mask[by * 128 + tid];
    else                cmaskS[tid - 128] = mask[bx * 128 + (tid - 128)];

    f32x4 acc[4][4];
    #pragma unroll
    for (int i = 0; i < 4; ++i)
        #pragma unroll
        for (int j = 0; j < 4; ++j) acc[i][j] = (f32x4)0.0f;

    const size_t arow0 = (size_t)by * 128;
    const size_t brow0 = (size_t)bx * 128;

    // ---- prologue: 2 tiles in flight (16 loads/thread outstanding) ----
    stage_tile(embb, arow0, brow0, 0, A0, B0, tid);
    stage_tile(embb, arow0, brow0, 1, A1, B1, tid);

    // ---- counted-vmcnt pipeline: never drain to 0 in steady state ----
    #pragma unroll 1
    for (int kb2 = 0; kb2 < 7; ++kb2) {
        asm volatile("s_waitcnt vmcnt(8)" ::: "memory");
        __builtin_amdgcn_s_barrier();
        compute_tile(A0, B0, wm, wn, lane, acc);
        __builtin_amdgcn_s_barrier();
        stage_tile(embb, arow0, brow0, 2 * kb2 + 2, A0, B0, tid);
        asm volatile("s_waitcnt vmcnt(8)" ::: "memory");
        __builtin_amdgcn_s_barrier();
        compute_tile(A1, B1, wm, wn, lane, acc);
        __builtin_amdgcn_s_barrier();
        stage_tile(embb, arow0, brow0, 2 * kb2 + 3, A1, B1, tid);
    }
    asm volatile("s_waitcnt vmcnt(8)" ::: "memory");
    __builtin_amdgcn_s_barrier();
    compute_tile(A0, B0, wm, wn, lane, acc);
    asm volatile("s_waitcnt vmcnt(0)" ::: "memory");
    __builtin_amdgcn_s_barrier();
    compute_tile(A1, B1, wm, wn, lane, acc);

    // C/D layout: col = lane&15, row = (lane>>4)*4 + reg   [m89-verified]
    const int lg = lane >> 4;
    const int lc = lane & 15;

    uint64_t cmR[4];
    #pragma unroll
    for (int nf = 0; nf < 4; ++nf) cmR[nf] = cmaskS[wn * 64 + nf * 16 + lc];

    // ---- exp in place; zero exact-diagonal elements (diag tiles only) ----
    // |sim| <= 14.3 so exp() spans [6e-7, 1.6e6]: no overflow, max-shift unnecessary
    const bool diagw = (bx == by) && (wm == wn);
    #pragma unroll
    for (int mf = 0; mf < 4; ++mf)
        #pragma unroll
        for (int nf = 0; nf < 4; ++nf) {
            const bool dmn = diagw && (mf == nf);
            #pragma unroll
            for (int rg = 0; rg < 4; ++rg) {
                float e = __expf(acc[mf][nf][rg] * TEMP_INV);
                if (dmn && (lc == lg * 4 + rg)) e = 0.0f;
                acc[mf][nf][rg] = e;
            }
        }

    // ---- row epilogue: plain (pos,neg) sums over this tile's cols ----
    #pragma unroll
    for (int mf = 0; mf < 4; ++mf) {
        #pragma unroll
        for (int rg = 0; rg < 4; ++rg) {
            const int r = wm * 64 + mf * 16 + lg * 4 + rg;
            const uint64_t rm = rmaskS[r];
            float sp = 0.0f, ss = 0.0f;
            #pragma unroll
            for (int nf = 0; nf < 4; ++nf) {
                const float e = acc[mf][nf][rg];
                ss += e;
                if (rm & cmR[nf]) sp += e;
            }
            #pragma unroll
            for (int o = 1; o < 16; o <<= 1) { sp += __shfl_xor(sp, o); ss += __shfl_xor(ss, o); }
            if (lc == 0) {
                atomicAdd(&psum[by * 128 + r], sp);
                atomicAdd(&nsum[by * 128 + r], ss);
            }
        }
    }

    // ---- col epilogue (symmetric contribution), skip on diagonal tiles ----
    if (bx != by) {
        #pragma unroll
        for (int nf = 0; nf < 4; ++nf) {
            const uint64_t cm = cmR[nf];
            float sp = 0.0f, ss = 0.0f;
            #pragma unroll
            for (int mf = 0; mf < 4; ++mf)
                #pragma unroll
                for (int rg = 0; rg < 4; ++rg) {
                    const float e = acc[mf][nf][rg];
                    ss += e;
                    if (rmaskS[wm * 64 + mf * 16 + lg * 4 + rg] & cm) sp += e;
                }
            sp += __shfl_xor(sp, 16); sp += __shfl_xor(sp, 32);
            ss += __shfl_xor(ss, 16); ss += __shfl_xor(ss, 32);
            if (lane < 16) {
                atomicAdd(&psum[bx * 128 + wn * 64 + nf * 16 + lc], sp);
                atomicAdd(&nsum[bx * 128 + wn * 64 + nf * 16 + lc], ss);
            }
        }
    }
}

// ---------------- kernel 3: final scalar (kernel boundary = full visibility) -
__global__ void final_kernel(const float* __restrict__ psum,
                             const float* __restrict__ nsum,
                             const float* __restrict__ w,
                             const float* __restrict__ bce,
                             float* __restrict__ out) {
    const int tid = threadIdx.x;   // 256
    float li = 0.0f, va = 0.0f, bc = 0.0f;
    #pragma unroll 4
    for (int k = 0; k < 16; ++k) {
        const int row = k * 256 + tid;
        const float p = psum[row];
        const float n = nsum[row];
        bc += bce[row];
        if (p > 0.0f) { va += 1.0f; li += -logf(p / (n + 1e-8f)) * w[row]; }
    }
    #pragma unroll
    for (int o = 1; o < 64; o <<= 1) {
        li += __shfl_xor(li, o); va += __shfl_xor(va, o); bc += __shfl_xor(bc, o);
    }
    __shared__ float sl[4], sv[4], sb[4];
    if ((tid & 63) == 0) { sl[tid >> 6] = li; sv[tid >> 6] = va; sb[tid >> 6] = bc; }
    __syncthreads();
    if (tid == 0) {
        const float L = sl[0] + sl[1] + sl[2] + sl[3];
        const float V = sv[0] + sv[1] + sv[2] + sv[3];
        const float B = sb[0] + sb[1] + sb[2] + sb[3];
        out[0] = B / (float)(NROWS * NCLS) + (V > 0.0f ? L / V : 0.0f);
    }
}

extern "C" void kernel_launch(void* const* d_in, const int* in_sizes, int n_in,
                              void* d_out, int out_size, void* d_ws, size_t ws_size,
                              hipStream_t stream) {
    const float* emb    = (const float*)d_in[0];
    const float* logits = (const float*)d_in[1];
    const int*   labels = (const int*)d_in[2];
    float* out = (float*)d_out;

    uint8_t* ws = (uint8_t*)d_ws;
    uint64_t*       mask  = (uint64_t*)(ws);                    // 32 KB
    float*          wrow  = (float*)(ws + 0x8000);              // 16 KB
    float*          bcer  = (float*)(ws + 0xC000);              // 16 KB
    float*          psum  = (float*)(ws + 0x10000);             // 16 KB
    float*          nsum  = (float*)(ws + 0x14000);             // 16 KB
    __hip_bfloat16* embb  = (__hip_bfloat16*)(ws + 0x20000);    // 8 MB

    prep_convert_kernel<<<CONV_BLOCKS + PREP_BLOCKS, 256, 0, stream>>>(
        emb, logits, labels, embb, mask, wrow, bcer, psum, nsum);
    sim_kernel<<<NTRI, 256, 0, stream>>>(embb, mask, psum, nsum);
    final_kernel<<<1, 256, 0, stream>>>(psum, nsum, wrow, bcer, out);
}